// Round 8
// baseline (693.636 us; speedup 1.0000x reference)
//
#include <hip/hip_runtime.h>

#define NN 100000
#define NE 1600000
#define F 128
#define SCAN_CHUNK 2048
#define NB_SCAN ((NN + SCAN_CHUNK - 1) / SCAN_CHUNK)   // 49
#define NBUCK ((NN + 255) >> 8)                         // 391 buckets of 256 nodes
#define EPB (NE / 256)                                  // 6250 edges per scatter block

typedef __bf16 bf16x8 __attribute__((ext_vector_type(8)));
typedef float  f32x4  __attribute__((ext_vector_type(4)));
typedef unsigned short ushort8v __attribute__((ext_vector_type(8)));
typedef unsigned short ushort4v __attribute__((ext_vector_type(4)));

__device__ inline float bf2f(unsigned short h) { return __uint_as_float(((unsigned int)h) << 16); }
__device__ inline unsigned short f2bf_rn(float f) {
    unsigned int u = __float_as_uint(f);
    return (unsigned short)((u + 0x7FFFu + ((u >> 16) & 1u)) >> 16);
}

// ---------------- CSR build ----------------
__global__ void k_hist(const int* __restrict__ dst, int* __restrict__ deg) {
    int stride = gridDim.x * blockDim.x;
    for (int e = blockIdx.x * blockDim.x + threadIdx.x; e < NE; e += stride)
        atomicAdd(&deg[dst[e]], 1);
}

__global__ void k_scan_part(const int* __restrict__ deg, int* __restrict__ partial) {
    __shared__ int sdata[256];
    int base = blockIdx.x * SCAN_CHUNK;
    int sum = 0;
    for (int j = threadIdx.x; j < SCAN_CHUNK; j += 256) {
        int idx = base + j;
        sum += (idx < NN) ? deg[idx] : 0;
    }
    sdata[threadIdx.x] = sum;
    __syncthreads();
    for (int s = 128; s > 0; s >>= 1) {
        if (threadIdx.x < s) sdata[threadIdx.x] += sdata[threadIdx.x + s];
        __syncthreads();
    }
    if (threadIdx.x == 0) partial[blockIdx.x] = sdata[0];
}

__global__ void k_scan_mid(int* __restrict__ partial) {
    if (threadIdx.x == 0) {
        int acc = 0;
        for (int i = 0; i < NB_SCAN; ++i) { int v = partial[i]; partial[i] = acc; acc += v; }
    }
}

__global__ void k_scan_final(const int* __restrict__ deg, const int* __restrict__ partial,
                             int* __restrict__ row_ptr, int* __restrict__ cursor) {
    __shared__ int svals[SCAN_CHUNK];
    __shared__ int ssum[256];
    int base = blockIdx.x * SCAN_CHUNK;
    for (int j = threadIdx.x; j < SCAN_CHUNK; j += 256) {
        int idx = base + j;
        svals[j] = (idx < NN) ? deg[idx] : 0;
    }
    __syncthreads();
    int t0 = threadIdx.x * 8;
    int loc[8];
    int s = 0;
#pragma unroll
    for (int k = 0; k < 8; ++k) { loc[k] = s; s += svals[t0 + k]; }
    ssum[threadIdx.x] = s;
    __syncthreads();
    for (int off = 1; off < 256; off <<= 1) {
        int v = (threadIdx.x >= off) ? ssum[threadIdx.x - off] : 0;
        __syncthreads();
        ssum[threadIdx.x] += v;
        __syncthreads();
    }
    int texcl = (threadIdx.x == 0) ? 0 : ssum[threadIdx.x - 1];
    int offbase = partial[blockIdx.x] + texcl;
#pragma unroll
    for (int k = 0; k < 8; ++k) {
        int idx = base + t0 + k;
        if (idx < NN) {
            int v = offbase + loc[k];
            row_ptr[idx] = v;
            cursor[idx]  = v;
        }
    }
    if (blockIdx.x == 0 && threadIdx.x == 0) row_ptr[NN] = NE;
}

__global__ void k_bcur(const int* __restrict__ row_ptr, int* __restrict__ bcur) {
    int t = blockIdx.x * 256 + threadIdx.x;
    if (t < NBUCK) bcur[t] = row_ptr[t << 8];
}

__global__ __launch_bounds__(256) void k_scatterA(const int* __restrict__ src,
                                                  const int* __restrict__ dst,
                                                  int* __restrict__ bcur,
                                                  uint2* __restrict__ scratch) {
    __shared__ uint2 sEdge[EPB];          // 50 KB
    __shared__ int cnt[512];
    __shared__ int scn[512];
    __shared__ int cntB[512];
    __shared__ int gbase[512];
    __shared__ int ssum[256];

    const int tid = threadIdx.x;
    const int ebase = blockIdx.x * EPB;

#pragma unroll
    for (int i = tid; i < 512; i += 256) { cnt[i] = 0; cntB[i] = 0; }
    __syncthreads();

    for (int i = tid; i < EPB; i += 256) {
        int b = dst[ebase + i] >> 8;
        atomicAdd(&cnt[b], 1);
    }
    __syncthreads();

    int c0 = cnt[2 * tid], c1 = cnt[2 * tid + 1];
    ssum[tid] = c0 + c1;
    __syncthreads();
    for (int off = 1; off < 256; off <<= 1) {
        int v = (tid >= off) ? ssum[tid - off] : 0;
        __syncthreads();
        ssum[tid] += v;
        __syncthreads();
    }
    int texcl = (tid == 0) ? 0 : ssum[tid - 1];
    scn[2 * tid] = texcl;
    scn[2 * tid + 1] = texcl + c0;
#pragma unroll
    for (int i = tid; i < NBUCK; i += 256) {
        int c = cnt[i];
        gbase[i] = c ? atomicAdd(&bcur[i], c) : 0;
    }
    __syncthreads();

    for (int i = tid; i < EPB; i += 256) {
        int s = src[ebase + i], d = dst[ebase + i];
        int b = d >> 8;
        int rank = atomicAdd(&cntB[b], 1);
        sEdge[scn[b] + rank] = make_uint2((unsigned)s, (unsigned)d);
    }
    __syncthreads();

    for (int i = tid; i < EPB; i += 256) {
        uint2 ed = sEdge[i];
        int b = (int)(ed.y >> 8);
        scratch[gbase[b] + (i - scn[b])] = ed;
    }
}

__global__ __launch_bounds__(256) void k_fillB(const int* __restrict__ row_ptr,
                                               const uint2* __restrict__ scratch,
                                               int* __restrict__ cursor,
                                               int* __restrict__ csr) {
    int b = blockIdx.x;
    int s = row_ptr[b << 8];
    int endNode = (b + 1) << 8; if (endNode > NN) endNode = NN;
    int e = row_ptr[endNode];
    for (int i = s + threadIdx.x; i < e; i += 256) {
        uint2 ed = scratch[i];
        int p = atomicAdd(&cursor[ed.y], 1);
        csr[p] = (int)ed.x;
    }
}

// ---------------- x -> bf16 (RTN) ----------------
__global__ void k_x2bf(const float* __restrict__ x, unsigned short* __restrict__ xb) {
    int idx = blockIdx.x * 256 + threadIdx.x;     // over float4s, NN*128/4 total
    float4 v = ((const float4*)x)[idx];
    ushort4v h;
    h.x = f2bf_rn(v.x);
    h.y = f2bf_rn(v.y);
    h.z = f2bf_rn(v.z);
    h.w = f2bf_rn(v.w);
    ((ushort4v*)xb)[idx] = h;
}

// ---------------- weight split: W[k][n] fp32 -> Wt_hi/Wt_lo [n][k] bf16 ----------------
struct WPack {
    const float* w[5];
    unsigned short* hi[5];
    unsigned short* lo[5];
};

__global__ void k_wsplit_all(WPack p) {
    int which = blockIdx.x >> 6;
    int idx = (blockIdx.x & 63) * 256 + threadIdx.x; // over n*128+k
    int n = idx >> 7, k = idx & 127;
    float v = p.w[which][k * 128 + n];
    unsigned short h = f2bf_rn(v);
    unsigned short l = f2bf_rn(v - bf2f(h));
    p.hi[which][idx] = h;
    p.lo[which][idx] = l;
}

// ---------------- aggregation: u[i] = h[i] + sum_{j in N(i)} h[j]  (bf16 world) ----------
// 16 lanes x 16B per row: one wave covers 4 nodes concurrently; 4-way neighbor unroll
// -> 16 independent row-loads (4 KB) in flight per wave.
__global__ __launch_bounds__(256) void k_agg_bf(const unsigned short* __restrict__ h,
                                                const int* __restrict__ row_ptr,
                                                const int* __restrict__ csr,
                                                unsigned short* __restrict__ u) {
    int g   = threadIdx.x >> 4;         // 0..15
    int l16 = threadIdx.x & 15;
    int node = blockIdx.x * 16 + g;     // 6250 blocks * 16 = 100000 exactly
    int lofs = l16 * 8;                 // 8 bf16 = 16 B per lane
    size_t base = (size_t)node * F + lofs;
    ushort8v sh = *(const ushort8v*)&h[base];
    float a[8];
#pragma unroll
    for (int k = 0; k < 8; ++k) a[k] = bf2f(sh[k]);
    int s = row_ptr[node], e = row_ptr[node + 1];
    int p = s;
    for (; p + 4 <= e; p += 4) {
        int j0 = csr[p], j1 = csr[p + 1], j2 = csr[p + 2], j3 = csr[p + 3];
        ushort8v v0 = *(const ushort8v*)&h[(size_t)j0 * F + lofs];
        ushort8v v1 = *(const ushort8v*)&h[(size_t)j1 * F + lofs];
        ushort8v v2 = *(const ushort8v*)&h[(size_t)j2 * F + lofs];
        ushort8v v3 = *(const ushort8v*)&h[(size_t)j3 * F + lofs];
#pragma unroll
        for (int k = 0; k < 8; ++k)
            a[k] += (bf2f(v0[k]) + bf2f(v1[k])) + (bf2f(v2[k]) + bf2f(v3[k]));
    }
    if (p + 2 <= e) {
        int j0 = csr[p], j1 = csr[p + 1];
        ushort8v v0 = *(const ushort8v*)&h[(size_t)j0 * F + lofs];
        ushort8v v1 = *(const ushort8v*)&h[(size_t)j1 * F + lofs];
#pragma unroll
        for (int k = 0; k < 8; ++k) a[k] += bf2f(v0[k]) + bf2f(v1[k]);
        p += 2;
    }
    if (p < e) {
        int j0 = csr[p];
        ushort8v v0 = *(const ushort8v*)&h[(size_t)j0 * F + lofs];
#pragma unroll
        for (int k = 0; k < 8; ++k) a[k] += bf2f(v0[k]);
    }
    ushort8v o;
#pragma unroll
    for (int k = 0; k < 8; ++k) o[k] = f2bf_rn(a[k]);
    *(ushort8v*)&u[base] = o;
}

// ---------------- MLP layer: 64-row tile for occupancy ----------------
// L3==0: H = (relu(A@W1+b1))@W2 + b2, written bf16.
// L3==1: out = relu(A@W1+b1) @ w32 + b32, fp32 [NN].
template <int L3>
__global__ __launch_bounds__(256, 4) void k_mlp(const unsigned short* __restrict__ A,
                                                const unsigned short* __restrict__ W1hi,
                                                const unsigned short* __restrict__ W1lo,
                                                const float* __restrict__ b1,
                                                const unsigned short* __restrict__ W2hi,
                                                const unsigned short* __restrict__ W2lo,
                                                const float* __restrict__ b2,
                                                const float* __restrict__ w32,
                                                const float* __restrict__ b32,
                                                unsigned short* __restrict__ H,
                                                float* __restrict__ out) {
    __shared__ __align__(16) unsigned short sA[64 * 128];   // 16 KB

    const int tid = threadIdx.x;
    const int row0 = blockIdx.x * 64;
    const int wave = tid >> 6;          // 0..3 -> rows [wave*16, wave*16+16)
    const int lane = tid & 63;
    const int m16  = lane & 15;
    const int quad = lane >> 4;

    // ---- stage A tile: lane-contiguous global reads, XOR-swizzled LDS writes ----
    {
        const ushort8v* g = (const ushort8v*)(A + (size_t)row0 * F);
#pragma unroll
        for (int i = 0; i < 4; ++i) {
            int fg = i * 256 + tid;              // 0..1023
            int r = fg >> 4, u = fg & 15;
            ushort8v v = {};
            if (row0 + r < NN) v = g[fg];
            *(ushort8v*)&sA[r * 128 + ((u ^ (r & 15)) << 3)] = v;
        }
    }
    __syncthreads();

    const int rowL = wave * 16 + m16;

    // ---- GEMM1 ----
    f32x4 acc[8] = {};
#pragma unroll
    for (int ks = 0; ks < 4; ++ks) {
        int u = ks * 4 + quad;
        bf16x8 a = *(const bf16x8*)&sA[rowL * 128 + ((u ^ (rowL & 15)) << 3)];
#pragma unroll
        for (int ct = 0; ct < 8; ++ct) {
            int widx = (ct * 16 + m16) * 128 + ks * 32 + quad * 8;
            bf16x8 bh = *(const bf16x8*)&W1hi[widx];
            bf16x8 bl = *(const bf16x8*)&W1lo[widx];
            acc[ct] = __builtin_amdgcn_mfma_f32_16x16x32_bf16(a, bh, acc[ct], 0, 0, 0);
            acc[ct] = __builtin_amdgcn_mfma_f32_16x16x32_bf16(a, bl, acc[ct], 0, 0, 0);
        }
    }

    if (L3) {
        float s[4] = {0.f, 0.f, 0.f, 0.f};
#pragma unroll
        for (int ct = 0; ct < 8; ++ct) {
            int col = ct * 16 + m16;
            float bv = b1[col];
            float wv = w32[col];
#pragma unroll
            for (int i = 0; i < 4; ++i) {
                float v = fmaxf(acc[ct][i] + bv, 0.f);
                s[i] += v * wv;
            }
        }
#pragma unroll
        for (int i = 0; i < 4; ++i) {
#pragma unroll
            for (int mask = 1; mask < 16; mask <<= 1)
                s[i] += __shfl_xor(s[i], mask, 64);
        }
        if (m16 == 0) {
#pragma unroll
            for (int i = 0; i < 4; ++i) {
                int row = row0 + wave * 16 + quad * 4 + i;
                if (row < NN) out[row] = s[i] + b32[0];
            }
        }
        return;
    }

    // ---- h1 = relu(acc+b1) -> bf16 into LDS (C-layout -> A-layout) ----
    __syncthreads();
#pragma unroll
    for (int ct = 0; ct < 8; ++ct) {
        int col = ct * 16 + m16;
        float bv = b1[col];
#pragma unroll
        for (int i = 0; i < 4; ++i) {
            int rL = wave * 16 + quad * 4 + i;
            float v = fmaxf(acc[ct][i] + bv, 0.f);
            sA[rL * 128 + (((col >> 3) ^ (rL & 15)) << 3) + (col & 7)] = f2bf_rn(v);
        }
    }
    __syncthreads();

    // ---- GEMM2 ----
    f32x4 acc2[8] = {};
#pragma unroll
    for (int ks = 0; ks < 4; ++ks) {
        int u = ks * 4 + quad;
        bf16x8 a = *(const bf16x8*)&sA[rowL * 128 + ((u ^ (rowL & 15)) << 3)];
#pragma unroll
        for (int ct = 0; ct < 8; ++ct) {
            int widx = (ct * 16 + m16) * 128 + ks * 32 + quad * 8;
            bf16x8 bh = *(const bf16x8*)&W2hi[widx];
            bf16x8 bl = *(const bf16x8*)&W2lo[widx];
            acc2[ct] = __builtin_amdgcn_mfma_f32_16x16x32_bf16(a, bh, acc2[ct], 0, 0, 0);
            acc2[ct] = __builtin_amdgcn_mfma_f32_16x16x32_bf16(a, bl, acc2[ct], 0, 0, 0);
        }
    }

    // ---- epilogue: bias -> bf16 -> LDS -> coalesced store ----
    __syncthreads();
#pragma unroll
    for (int ct = 0; ct < 8; ++ct) {
        int col = ct * 16 + m16;
        float bv = b2[col];
#pragma unroll
        for (int i = 0; i < 4; ++i) {
            int rL = wave * 16 + quad * 4 + i;
            float v = acc2[ct][i] + bv;
            sA[rL * 128 + (((col >> 3) ^ (rL & 15)) << 3) + (col & 7)] = f2bf_rn(v);
        }
    }
    __syncthreads();
    {
        ushort8v* go = (ushort8v*)(H + (size_t)row0 * F);
#pragma unroll
        for (int i = 0; i < 4; ++i) {
            int fg = i * 256 + tid;
            int r = fg >> 4, u = fg & 15;
            if (row0 + r < NN)
                go[fg] = *(const ushort8v*)&sA[r * 128 + ((u ^ (r & 15)) << 3)];
        }
    }
}

// ---------------- launch ----------------
static inline size_t align256(size_t x) { return (x + 255) & ~(size_t)255; }

extern "C" void kernel_launch(void* const* d_in, const int* in_sizes, int n_in,
                              void* d_out, int out_size, void* d_ws, size_t ws_size,
                              hipStream_t stream) {
    const float* x   = (const float*)d_in[0];
    const int*   ei  = (const int*)d_in[1];
    const float* w11 = (const float*)d_in[2];
    const float* b11 = (const float*)d_in[3];
    const float* w12 = (const float*)d_in[4];
    const float* b12 = (const float*)d_in[5];
    const float* w21 = (const float*)d_in[6];
    const float* b21 = (const float*)d_in[7];
    const float* w22 = (const float*)d_in[8];
    const float* b22 = (const float*)d_in[9];
    const float* w31 = (const float*)d_in[10];
    const float* b31 = (const float*)d_in[11];
    const float* w32 = (const float*)d_in[12];
    const float* b32 = (const float*)d_in[13];
    float* out = (float*)d_out;

    const int* src = ei;
    const int* dst = ei + NE;

    char* ws = (char*)d_ws;
    size_t off = 0;
    unsigned short* Abuf = (unsigned short*)(ws + off); off += align256((size_t)NN * F * 2);
    unsigned short* Bbuf = (unsigned short*)(ws + off); off += align256((size_t)NN * F * 2);
    int* deg     = (int*)(ws + off); off += align256((size_t)NN * 4);
    int* row_ptr = (int*)(ws + off); off += align256((size_t)(NN + 1) * 4);
    int* cursor  = (int*)(ws + off); off += align256((size_t)NN * 4);
    int* partial = (int*)(ws + off); off += align256((size_t)NB_SCAN * 4);
    int* bcur    = (int*)(ws + off); off += align256((size_t)NBUCK * 4);
    int* csr     = (int*)(ws + off); off += align256((size_t)NE * 4);
    uint2* scratch = (uint2*)(ws + off); off += align256((size_t)NE * 8);
    unsigned short* whi[5];
    unsigned short* wlo[5];
    for (int i = 0; i < 5; ++i) {
        whi[i] = (unsigned short*)(ws + off); off += align256((size_t)128 * 128 * 2);
        wlo[i] = (unsigned short*)(ws + off); off += align256((size_t)128 * 128 * 2);
    }
    (void)ws_size;

    // ---- weight + input conversion ----
    WPack wp;
    wp.w[0] = w11; wp.w[1] = w12; wp.w[2] = w21; wp.w[3] = w22; wp.w[4] = w31;
    for (int i = 0; i < 5; ++i) { wp.hi[i] = whi[i]; wp.lo[i] = wlo[i]; }
    k_wsplit_all<<<320, 256, 0, stream>>>(wp);
    k_x2bf<<<(NN * F / 4 + 255) / 256, 256, 0, stream>>>(x, Abuf);

    // ---- CSR build ----
    (void)hipMemsetAsync(deg, 0, (size_t)NN * 4, stream);
    k_hist<<<2048, 256, 0, stream>>>(dst, deg);
    k_scan_part<<<NB_SCAN, 256, 0, stream>>>(deg, partial);
    k_scan_mid<<<1, 64, 0, stream>>>(partial);
    k_scan_final<<<NB_SCAN, 256, 0, stream>>>(deg, partial, row_ptr, cursor);
    k_bcur<<<(NBUCK + 255) / 256, 256, 0, stream>>>(row_ptr, bcur);
    k_scatterA<<<256, 256, 0, stream>>>(src, dst, bcur, scratch);
    k_fillB<<<NBUCK, 256, 0, stream>>>(row_ptr, scratch, cursor, csr);

    const int aggBlocks = NN / 16;              // 6250
    const int mlpBlocks = (NN + 63) / 64;       // 1563

    // ---- layer 1 ----
    k_agg_bf<<<aggBlocks, 256, 0, stream>>>(Abuf, row_ptr, csr, Bbuf);
    k_mlp<0><<<mlpBlocks, 256, 0, stream>>>(Bbuf, whi[0], wlo[0], b11, whi[1], wlo[1], b12,
                                            nullptr, nullptr, Abuf, nullptr);
    // ---- layer 2 ----
    k_agg_bf<<<aggBlocks, 256, 0, stream>>>(Abuf, row_ptr, csr, Bbuf);
    k_mlp<0><<<mlpBlocks, 256, 0, stream>>>(Bbuf, whi[2], wlo[2], b21, whi[3], wlo[3], b22,
                                            nullptr, nullptr, Abuf, nullptr);
    // ---- layer 3 ----
    k_agg_bf<<<aggBlocks, 256, 0, stream>>>(Abuf, row_ptr, csr, Bbuf);
    k_mlp<1><<<mlpBlocks, 256, 0, stream>>>(Bbuf, whi[4], wlo[4], b31, nullptr, nullptr, nullptr,
                                            w32, b32, nullptr, out);
}

// Round 9
// 581.869 us; speedup vs baseline: 1.1921x; 1.1921x over previous
//
#include <hip/hip_runtime.h>

#define NN 100000
#define NE 1600000
#define F 128
#define SCAN_CHUNK 2048
#define NB_SCAN ((NN + SCAN_CHUNK - 1) / SCAN_CHUNK)   // 49
#define NBUCK ((NN + 255) >> 8)                         // 391 buckets of 256 nodes
#define EPB (NE / 256)                                  // 6250 edges per scatter block

typedef __bf16 bf16x8 __attribute__((ext_vector_type(8)));
typedef float  f32x4  __attribute__((ext_vector_type(4)));
typedef unsigned short ushort8v __attribute__((ext_vector_type(8)));
typedef unsigned short ushort4v __attribute__((ext_vector_type(4)));

__device__ inline float bf2f(unsigned short h) { return __uint_as_float(((unsigned int)h) << 16); }
__device__ inline unsigned short f2bf_rn(float f) {
    unsigned int u = __float_as_uint(f);
    return (unsigned short)((u + 0x7FFFu + ((u >> 16) & 1u)) >> 16);
}

// ---------------- CSR build ----------------
__global__ void k_hist(const int* __restrict__ dst, int* __restrict__ deg) {
    int stride = gridDim.x * blockDim.x;
    for (int e = blockIdx.x * blockDim.x + threadIdx.x; e < NE; e += stride)
        atomicAdd(&deg[dst[e]], 1);
}

__global__ void k_scan_part(const int* __restrict__ deg, int* __restrict__ partial) {
    __shared__ int sdata[256];
    int base = blockIdx.x * SCAN_CHUNK;
    int sum = 0;
    for (int j = threadIdx.x; j < SCAN_CHUNK; j += 256) {
        int idx = base + j;
        sum += (idx < NN) ? deg[idx] : 0;
    }
    sdata[threadIdx.x] = sum;
    __syncthreads();
    for (int s = 128; s > 0; s >>= 1) {
        if (threadIdx.x < s) sdata[threadIdx.x] += sdata[threadIdx.x + s];
        __syncthreads();
    }
    if (threadIdx.x == 0) partial[blockIdx.x] = sdata[0];
}

__global__ void k_scan_mid(int* __restrict__ partial) {
    if (threadIdx.x == 0) {
        int acc = 0;
        for (int i = 0; i < NB_SCAN; ++i) { int v = partial[i]; partial[i] = acc; acc += v; }
    }
}

__global__ void k_scan_final(const int* __restrict__ deg, const int* __restrict__ partial,
                             int* __restrict__ row_ptr, int* __restrict__ cursor) {
    __shared__ int svals[SCAN_CHUNK];
    __shared__ int ssum[256];
    int base = blockIdx.x * SCAN_CHUNK;
    for (int j = threadIdx.x; j < SCAN_CHUNK; j += 256) {
        int idx = base + j;
        svals[j] = (idx < NN) ? deg[idx] : 0;
    }
    __syncthreads();
    int t0 = threadIdx.x * 8;
    int loc[8];
    int s = 0;
#pragma unroll
    for (int k = 0; k < 8; ++k) { loc[k] = s; s += svals[t0 + k]; }
    ssum[threadIdx.x] = s;
    __syncthreads();
    for (int off = 1; off < 256; off <<= 1) {
        int v = (threadIdx.x >= off) ? ssum[threadIdx.x - off] : 0;
        __syncthreads();
        ssum[threadIdx.x] += v;
        __syncthreads();
    }
    int texcl = (threadIdx.x == 0) ? 0 : ssum[threadIdx.x - 1];
    int offbase = partial[blockIdx.x] + texcl;
#pragma unroll
    for (int k = 0; k < 8; ++k) {
        int idx = base + t0 + k;
        if (idx < NN) {
            int v = offbase + loc[k];
            row_ptr[idx] = v;
            cursor[idx]  = v;
        }
    }
    if (blockIdx.x == 0 && threadIdx.x == 0) row_ptr[NN] = NE;
}

__global__ void k_bcur(const int* __restrict__ row_ptr, int* __restrict__ bcur) {
    int t = blockIdx.x * 256 + threadIdx.x;
    if (t < NBUCK) bcur[t] = row_ptr[t << 8];
}

__global__ __launch_bounds__(256) void k_scatterA(const int* __restrict__ src,
                                                  const int* __restrict__ dst,
                                                  int* __restrict__ bcur,
                                                  uint2* __restrict__ scratch) {
    __shared__ uint2 sEdge[EPB];          // 50 KB
    __shared__ int cnt[512];
    __shared__ int scn[512];
    __shared__ int cntB[512];
    __shared__ int gbase[512];
    __shared__ int ssum[256];

    const int tid = threadIdx.x;
    const int ebase = blockIdx.x * EPB;

#pragma unroll
    for (int i = tid; i < 512; i += 256) { cnt[i] = 0; cntB[i] = 0; }
    __syncthreads();

    for (int i = tid; i < EPB; i += 256) {
        int b = dst[ebase + i] >> 8;
        atomicAdd(&cnt[b], 1);
    }
    __syncthreads();

    int c0 = cnt[2 * tid], c1 = cnt[2 * tid + 1];
    ssum[tid] = c0 + c1;
    __syncthreads();
    for (int off = 1; off < 256; off <<= 1) {
        int v = (tid >= off) ? ssum[tid - off] : 0;
        __syncthreads();
        ssum[tid] += v;
        __syncthreads();
    }
    int texcl = (tid == 0) ? 0 : ssum[tid - 1];
    scn[2 * tid] = texcl;
    scn[2 * tid + 1] = texcl + c0;
#pragma unroll
    for (int i = tid; i < NBUCK; i += 256) {
        int c = cnt[i];
        gbase[i] = c ? atomicAdd(&bcur[i], c) : 0;
    }
    __syncthreads();

    for (int i = tid; i < EPB; i += 256) {
        int s = src[ebase + i], d = dst[ebase + i];
        int b = d >> 8;
        int rank = atomicAdd(&cntB[b], 1);
        sEdge[scn[b] + rank] = make_uint2((unsigned)s, (unsigned)d);
    }
    __syncthreads();

    for (int i = tid; i < EPB; i += 256) {
        uint2 ed = sEdge[i];
        int b = (int)(ed.y >> 8);
        scratch[gbase[b] + (i - scn[b])] = ed;
    }
}

__global__ __launch_bounds__(256) void k_fillB(const int* __restrict__ row_ptr,
                                               const uint2* __restrict__ scratch,
                                               int* __restrict__ cursor,
                                               int* __restrict__ csr) {
    int b = blockIdx.x;
    int s = row_ptr[b << 8];
    int endNode = (b + 1) << 8; if (endNode > NN) endNode = NN;
    int e = row_ptr[endNode];
    for (int i = s + threadIdx.x; i < e; i += 256) {
        uint2 ed = scratch[i];
        int p = atomicAdd(&cursor[ed.y], 1);
        csr[p] = (int)ed.x;
    }
}

// ---------------- x -> bf16 (RTN) ----------------
__global__ void k_x2bf(const float* __restrict__ x, unsigned short* __restrict__ xb) {
    int idx = blockIdx.x * 256 + threadIdx.x;     // over float4s, NN*128/4 total
    float4 v = ((const float4*)x)[idx];
    ushort4v h;
    h.x = f2bf_rn(v.x);
    h.y = f2bf_rn(v.y);
    h.z = f2bf_rn(v.z);
    h.w = f2bf_rn(v.w);
    ((ushort4v*)xb)[idx] = h;
}

// ---------------- weight split: W[k][n] fp32 -> Wt_hi/Wt_lo [n][k] bf16 ----------------
struct WPack {
    const float* w[5];
    unsigned short* hi[5];
    unsigned short* lo[5];
};

__global__ void k_wsplit_all(WPack p) {
    int which = blockIdx.x >> 6;
    int idx = (blockIdx.x & 63) * 256 + threadIdx.x; // over n*128+k
    int n = idx >> 7, k = idx & 127;
    float v = p.w[which][k * 128 + n];
    unsigned short h = f2bf_rn(v);
    unsigned short l = f2bf_rn(v - bf2f(h));
    p.hi[which][idx] = h;
    p.lo[which][idx] = l;
}

// ---------------- aggregation (bf16): 16 lanes x 16B per row, 4-way unroll ----------------
__global__ __launch_bounds__(256) void k_agg_bf(const unsigned short* __restrict__ h,
                                                const int* __restrict__ row_ptr,
                                                const int* __restrict__ csr,
                                                unsigned short* __restrict__ u) {
    int g   = threadIdx.x >> 4;         // 0..15
    int l16 = threadIdx.x & 15;
    int node = blockIdx.x * 16 + g;     // 6250 blocks * 16 = 100000 exactly
    int lofs = l16 * 8;                 // 8 bf16 = 16 B per lane
    size_t base = (size_t)node * F + lofs;
    ushort8v sh = *(const ushort8v*)&h[base];
    float a[8];
#pragma unroll
    for (int k = 0; k < 8; ++k) a[k] = bf2f(sh[k]);
    int s = row_ptr[node], e = row_ptr[node + 1];
    int p = s;
    for (; p + 4 <= e; p += 4) {
        int j0 = csr[p], j1 = csr[p + 1], j2 = csr[p + 2], j3 = csr[p + 3];
        ushort8v v0 = *(const ushort8v*)&h[(size_t)j0 * F + lofs];
        ushort8v v1 = *(const ushort8v*)&h[(size_t)j1 * F + lofs];
        ushort8v v2 = *(const ushort8v*)&h[(size_t)j2 * F + lofs];
        ushort8v v3 = *(const ushort8v*)&h[(size_t)j3 * F + lofs];
#pragma unroll
        for (int k = 0; k < 8; ++k)
            a[k] += (bf2f(v0[k]) + bf2f(v1[k])) + (bf2f(v2[k]) + bf2f(v3[k]));
    }
    if (p + 2 <= e) {
        int j0 = csr[p], j1 = csr[p + 1];
        ushort8v v0 = *(const ushort8v*)&h[(size_t)j0 * F + lofs];
        ushort8v v1 = *(const ushort8v*)&h[(size_t)j1 * F + lofs];
#pragma unroll
        for (int k = 0; k < 8; ++k) a[k] += bf2f(v0[k]) + bf2f(v1[k]);
        p += 2;
    }
    if (p < e) {
        int j0 = csr[p];
        ushort8v v0 = *(const ushort8v*)&h[(size_t)j0 * F + lofs];
#pragma unroll
        for (int k = 0; k < 8; ++k) a[k] += bf2f(v0[k]);
    }
    ushort8v o;
#pragma unroll
    for (int k = 0; k < 8; ++k) o[k] = f2bf_rn(a[k]);
    *(ushort8v*)&u[base] = o;
}

// ---------------- MLP layer: 128-row tile, quadrant waves (64 rows x 64 cols) ----------------
// wave w: rg=w>>1 rows [64rg,64rg+64), cg=w&1 cols [64cg,64cg+64).
// W-reads per wave = its col slice only (2x less than full-width waves).
// L3==0: H = (relu(A@W1+b1))@W2 + b2, bf16.  L3==1: out = relu(A@W1+b1)@w32 + b32, fp32.
template <int L3>
__global__ __launch_bounds__(256, 3) void k_mlp(const unsigned short* __restrict__ A,
                                                const unsigned short* __restrict__ W1hi,
                                                const unsigned short* __restrict__ W1lo,
                                                const float* __restrict__ b1,
                                                const unsigned short* __restrict__ W2hi,
                                                const unsigned short* __restrict__ W2lo,
                                                const float* __restrict__ b2,
                                                const float* __restrict__ w32,
                                                const float* __restrict__ b32,
                                                unsigned short* __restrict__ H,
                                                float* __restrict__ out) {
    __shared__ __align__(16) unsigned short sA[128 * 128];   // 32 KB

    const int tid = threadIdx.x;
    const int row0 = blockIdx.x * 128;
    const int wave = tid >> 6;
    const int lane = tid & 63;
    const int m16  = lane & 15;
    const int quad = lane >> 4;
    const int rg   = wave >> 1;          // 0..1
    const int cg   = wave & 1;           // 0..1

    // ---- stage A tile: lane-contiguous global reads, XOR-swizzled LDS writes ----
    {
        const ushort8v* g = (const ushort8v*)(A + (size_t)row0 * F);
#pragma unroll
        for (int i = 0; i < 8; ++i) {
            int fg = i * 256 + tid;              // 0..2047
            int r = fg >> 4, u = fg & 15;
            ushort8v v = {};
            if (row0 + r < NN) v = g[fg];
            *(ushort8v*)&sA[r * 128 + ((u ^ (r & 15)) << 3)] = v;
        }
    }
    __syncthreads();

    // ---- GEMM1 (quadrant) ----
    f32x4 acc[4][4] = {};
#pragma unroll
    for (int ks = 0; ks < 4; ++ks) {
        bf16x8 a[4];
#pragma unroll
        for (int rt = 0; rt < 4; ++rt) {
            int rowL = rg * 64 + rt * 16 + m16;
            int u = ks * 4 + quad;
            a[rt] = *(const bf16x8*)&sA[rowL * 128 + ((u ^ (rowL & 15)) << 3)];
        }
#pragma unroll
        for (int ct = 0; ct < 4; ++ct) {
            int widx = (cg * 64 + ct * 16 + m16) * 128 + ks * 32 + quad * 8;
            bf16x8 bh = *(const bf16x8*)&W1hi[widx];
            bf16x8 bl = *(const bf16x8*)&W1lo[widx];
#pragma unroll
            for (int rt = 0; rt < 4; ++rt) {
                acc[rt][ct] = __builtin_amdgcn_mfma_f32_16x16x32_bf16(a[rt], bh, acc[rt][ct], 0, 0, 0);
                acc[rt][ct] = __builtin_amdgcn_mfma_f32_16x16x32_bf16(a[rt], bl, acc[rt][ct], 0, 0, 0);
            }
        }
    }

    if (L3) {
        // partial dot over this wave's 64 cols; combine across cg via LDS (alias sA)
        float* psf = (float*)sA;     // 128 rows x 2 cg
        __syncthreads();             // all sA reads complete before overwrite
#pragma unroll
        for (int rt = 0; rt < 4; ++rt) {
            float s[4] = {0.f, 0.f, 0.f, 0.f};
#pragma unroll
            for (int ct = 0; ct < 4; ++ct) {
                int col = cg * 64 + ct * 16 + m16;
                float bv = b1[col];
                float wv = w32[col];
#pragma unroll
                for (int i = 0; i < 4; ++i) {
                    float v = fmaxf(acc[rt][ct][i] + bv, 0.f);
                    s[i] += v * wv;
                }
            }
#pragma unroll
            for (int i = 0; i < 4; ++i) {
#pragma unroll
                for (int mask = 1; mask < 16; mask <<= 1)
                    s[i] += __shfl_xor(s[i], mask, 64);
            }
            if (m16 == 0) {
#pragma unroll
                for (int i = 0; i < 4; ++i) {
                    int rowL = rg * 64 + rt * 16 + quad * 4 + i;
                    psf[rowL * 2 + cg] = s[i];
                }
            }
        }
        __syncthreads();
        if (tid < 128) {
            int row = row0 + tid;
            if (row < NN) out[row] = psf[tid * 2] + psf[tid * 2 + 1] + b32[0];
        }
        return;
    }

    // ---- h1 = relu(acc+b1) -> bf16 into LDS quadrant (C-layout -> A-layout) ----
    __syncthreads();
#pragma unroll
    for (int rt = 0; rt < 4; ++rt) {
#pragma unroll
        for (int ct = 0; ct < 4; ++ct) {
            int col = cg * 64 + ct * 16 + m16;
            float bv = b1[col];
#pragma unroll
            for (int i = 0; i < 4; ++i) {
                int rL = rg * 64 + rt * 16 + quad * 4 + i;
                float v = fmaxf(acc[rt][ct][i] + bv, 0.f);
                sA[rL * 128 + (((col >> 3) ^ (rL & 15)) << 3) + (col & 7)] = f2bf_rn(v);
            }
        }
    }
    __syncthreads();

    // ---- GEMM2 (quadrant) ----
    f32x4 acc2[4][4] = {};
#pragma unroll
    for (int ks = 0; ks < 4; ++ks) {
        bf16x8 a[4];
#pragma unroll
        for (int rt = 0; rt < 4; ++rt) {
            int rowL = rg * 64 + rt * 16 + m16;
            int u = ks * 4 + quad;
            a[rt] = *(const bf16x8*)&sA[rowL * 128 + ((u ^ (rowL & 15)) << 3)];
        }
#pragma unroll
        for (int ct = 0; ct < 4; ++ct) {
            int widx = (cg * 64 + ct * 16 + m16) * 128 + ks * 32 + quad * 8;
            bf16x8 bh = *(const bf16x8*)&W2hi[widx];
            bf16x8 bl = *(const bf16x8*)&W2lo[widx];
#pragma unroll
            for (int rt = 0; rt < 4; ++rt) {
                acc2[rt][ct] = __builtin_amdgcn_mfma_f32_16x16x32_bf16(a[rt], bh, acc2[rt][ct], 0, 0, 0);
                acc2[rt][ct] = __builtin_amdgcn_mfma_f32_16x16x32_bf16(a[rt], bl, acc2[rt][ct], 0, 0, 0);
            }
        }
    }

    // ---- epilogue: bias -> bf16 -> LDS -> coalesced store ----
    __syncthreads();
#pragma unroll
    for (int rt = 0; rt < 4; ++rt) {
#pragma unroll
        for (int ct = 0; ct < 4; ++ct) {
            int col = cg * 64 + ct * 16 + m16;
            float bv = b2[col];
#pragma unroll
            for (int i = 0; i < 4; ++i) {
                int rL = rg * 64 + rt * 16 + quad * 4 + i;
                float v = acc2[rt][ct][i] + bv;
                sA[rL * 128 + (((col >> 3) ^ (rL & 15)) << 3) + (col & 7)] = f2bf_rn(v);
            }
        }
    }
    __syncthreads();
    {
        ushort8v* go = (ushort8v*)(H + (size_t)row0 * F);
#pragma unroll
        for (int i = 0; i < 8; ++i) {
            int fg = i * 256 + tid;
            int r = fg >> 4, u = fg & 15;
            if (row0 + r < NN)
                go[fg] = *(const ushort8v*)&sA[r * 128 + ((u ^ (r & 15)) << 3)];
        }
    }
}

// ---------------- launch ----------------
static inline size_t align256(size_t x) { return (x + 255) & ~(size_t)255; }

extern "C" void kernel_launch(void* const* d_in, const int* in_sizes, int n_in,
                              void* d_out, int out_size, void* d_ws, size_t ws_size,
                              hipStream_t stream) {
    const float* x   = (const float*)d_in[0];
    const int*   ei  = (const int*)d_in[1];
    const float* w11 = (const float*)d_in[2];
    const float* b11 = (const float*)d_in[3];
    const float* w12 = (const float*)d_in[4];
    const float* b12 = (const float*)d_in[5];
    const float* w21 = (const float*)d_in[6];
    const float* b21 = (const float*)d_in[7];
    const float* w22 = (const float*)d_in[8];
    const float* b22 = (const float*)d_in[9];
    const float* w31 = (const float*)d_in[10];
    const float* b31 = (const float*)d_in[11];
    const float* w32 = (const float*)d_in[12];
    const float* b32 = (const float*)d_in[13];
    float* out = (float*)d_out;

    const int* src = ei;
    const int* dst = ei + NE;

    char* ws = (char*)d_ws;
    size_t off = 0;
    unsigned short* Abuf = (unsigned short*)(ws + off); off += align256((size_t)NN * F * 2);
    unsigned short* Bbuf = (unsigned short*)(ws + off); off += align256((size_t)NN * F * 2);
    int* deg     = (int*)(ws + off); off += align256((size_t)NN * 4);
    int* row_ptr = (int*)(ws + off); off += align256((size_t)(NN + 1) * 4);
    int* cursor  = (int*)(ws + off); off += align256((size_t)NN * 4);
    int* partial = (int*)(ws + off); off += align256((size_t)NB_SCAN * 4);
    int* bcur    = (int*)(ws + off); off += align256((size_t)NBUCK * 4);
    int* csr     = (int*)(ws + off); off += align256((size_t)NE * 4);
    uint2* scratch = (uint2*)(ws + off); off += align256((size_t)NE * 8);
    unsigned short* whi[5];
    unsigned short* wlo[5];
    for (int i = 0; i < 5; ++i) {
        whi[i] = (unsigned short*)(ws + off); off += align256((size_t)128 * 128 * 2);
        wlo[i] = (unsigned short*)(ws + off); off += align256((size_t)128 * 128 * 2);
    }
    (void)ws_size;

    // ---- weight + input conversion ----
    WPack wp;
    wp.w[0] = w11; wp.w[1] = w12; wp.w[2] = w21; wp.w[3] = w22; wp.w[4] = w31;
    for (int i = 0; i < 5; ++i) { wp.hi[i] = whi[i]; wp.lo[i] = wlo[i]; }
    k_wsplit_all<<<320, 256, 0, stream>>>(wp);
    k_x2bf<<<(NN * F / 4 + 255) / 256, 256, 0, stream>>>(x, Abuf);

    // ---- CSR build ----
    (void)hipMemsetAsync(deg, 0, (size_t)NN * 4, stream);
    k_hist<<<2048, 256, 0, stream>>>(dst, deg);
    k_scan_part<<<NB_SCAN, 256, 0, stream>>>(deg, partial);
    k_scan_mid<<<1, 64, 0, stream>>>(partial);
    k_scan_final<<<NB_SCAN, 256, 0, stream>>>(deg, partial, row_ptr, cursor);
    k_bcur<<<(NBUCK + 255) / 256, 256, 0, stream>>>(row_ptr, bcur);
    k_scatterA<<<256, 256, 0, stream>>>(src, dst, bcur, scratch);
    k_fillB<<<NBUCK, 256, 0, stream>>>(row_ptr, scratch, cursor, csr);

    const int aggBlocks = NN / 16;              // 6250
    const int mlpBlocks = (NN + 127) / 128;     // 782

    // ---- layer 1 ----
    k_agg_bf<<<aggBlocks, 256, 0, stream>>>(Abuf, row_ptr, csr, Bbuf);
    k_mlp<0><<<mlpBlocks, 256, 0, stream>>>(Bbuf, whi[0], wlo[0], b11, whi[1], wlo[1], b12,
                                            nullptr, nullptr, Abuf, nullptr);
    // ---- layer 2 ----
    k_agg_bf<<<aggBlocks, 256, 0, stream>>>(Abuf, row_ptr, csr, Bbuf);
    k_mlp<0><<<mlpBlocks, 256, 0, stream>>>(Bbuf, whi[2], wlo[2], b21, whi[3], wlo[3], b22,
                                            nullptr, nullptr, Abuf, nullptr);
    // ---- layer 3 ----
    k_agg_bf<<<aggBlocks, 256, 0, stream>>>(Abuf, row_ptr, csr, Bbuf);
    k_mlp<1><<<mlpBlocks, 256, 0, stream>>>(Bbuf, whi[4], wlo[4], b31, nullptr, nullptr, nullptr,
                                            w32, b32, nullptr, out);
}

// Round 10
// 533.093 us; speedup vs baseline: 1.3012x; 1.0915x over previous
//
#include <hip/hip_runtime.h>

#define NN 100000
#define NE 1600000
#define F 128
#define SCAN_CHUNK 2048
#define NB_SCAN ((NN + SCAN_CHUNK - 1) / SCAN_CHUNK)   // 49
#define NBUCK ((NN + 255) >> 8)                         // 391 buckets of 256 nodes
#define EPB (NE / 256)                                  // 6250 edges per scatter block

typedef _Float16 f16x8 __attribute__((ext_vector_type(8)));
typedef float    f32x4 __attribute__((ext_vector_type(4)));
typedef unsigned short ushort8v __attribute__((ext_vector_type(8)));
typedef unsigned short ushort4v __attribute__((ext_vector_type(4)));

__device__ inline unsigned short f2h(float f) {
    _Float16 h = (_Float16)f;                       // RTN
    return __builtin_bit_cast(unsigned short, h);
}
__device__ inline float h2f(unsigned short u) {
    return (float)__builtin_bit_cast(_Float16, u);
}

// ---------------- CSR build ----------------
__global__ void k_hist(const int* __restrict__ dst, int* __restrict__ deg) {
    int stride = gridDim.x * blockDim.x;
    for (int e = blockIdx.x * blockDim.x + threadIdx.x; e < NE; e += stride)
        atomicAdd(&deg[dst[e]], 1);
}

__global__ void k_scan_part(const int* __restrict__ deg, int* __restrict__ partial) {
    __shared__ int sdata[256];
    int base = blockIdx.x * SCAN_CHUNK;
    int sum = 0;
    for (int j = threadIdx.x; j < SCAN_CHUNK; j += 256) {
        int idx = base + j;
        sum += (idx < NN) ? deg[idx] : 0;
    }
    sdata[threadIdx.x] = sum;
    __syncthreads();
    for (int s = 128; s > 0; s >>= 1) {
        if (threadIdx.x < s) sdata[threadIdx.x] += sdata[threadIdx.x + s];
        __syncthreads();
    }
    if (threadIdx.x == 0) partial[blockIdx.x] = sdata[0];
}

__global__ void k_scan_mid(int* __restrict__ partial) {
    if (threadIdx.x == 0) {
        int acc = 0;
        for (int i = 0; i < NB_SCAN; ++i) { int v = partial[i]; partial[i] = acc; acc += v; }
    }
}

__global__ void k_scan_final(const int* __restrict__ deg, const int* __restrict__ partial,
                             int* __restrict__ row_ptr, int* __restrict__ cursor) {
    __shared__ int svals[SCAN_CHUNK];
    __shared__ int ssum[256];
    int base = blockIdx.x * SCAN_CHUNK;
    for (int j = threadIdx.x; j < SCAN_CHUNK; j += 256) {
        int idx = base + j;
        svals[j] = (idx < NN) ? deg[idx] : 0;
    }
    __syncthreads();
    int t0 = threadIdx.x * 8;
    int loc[8];
    int s = 0;
#pragma unroll
    for (int k = 0; k < 8; ++k) { loc[k] = s; s += svals[t0 + k]; }
    ssum[threadIdx.x] = s;
    __syncthreads();
    for (int off = 1; off < 256; off <<= 1) {
        int v = (threadIdx.x >= off) ? ssum[threadIdx.x - off] : 0;
        __syncthreads();
        ssum[threadIdx.x] += v;
        __syncthreads();
    }
    int texcl = (threadIdx.x == 0) ? 0 : ssum[threadIdx.x - 1];
    int offbase = partial[blockIdx.x] + texcl;
#pragma unroll
    for (int k = 0; k < 8; ++k) {
        int idx = base + t0 + k;
        if (idx < NN) {
            int v = offbase + loc[k];
            row_ptr[idx] = v;
            cursor[idx]  = v;
        }
    }
    if (blockIdx.x == 0 && threadIdx.x == 0) row_ptr[NN] = NE;
}

__global__ void k_bcur(const int* __restrict__ row_ptr, int* __restrict__ bcur) {
    int t = blockIdx.x * 256 + threadIdx.x;
    if (t < NBUCK) bcur[t] = row_ptr[t << 8];
}

__global__ __launch_bounds__(256) void k_scatterA(const int* __restrict__ src,
                                                  const int* __restrict__ dst,
                                                  int* __restrict__ bcur,
                                                  uint2* __restrict__ scratch) {
    __shared__ uint2 sEdge[EPB];          // 50 KB
    __shared__ int cnt[512];
    __shared__ int scn[512];
    __shared__ int cntB[512];
    __shared__ int gbase[512];
    __shared__ int ssum[256];

    const int tid = threadIdx.x;
    const int ebase = blockIdx.x * EPB;

#pragma unroll
    for (int i = tid; i < 512; i += 256) { cnt[i] = 0; cntB[i] = 0; }
    __syncthreads();

    for (int i = tid; i < EPB; i += 256) {
        int b = dst[ebase + i] >> 8;
        atomicAdd(&cnt[b], 1);
    }
    __syncthreads();

    int c0 = cnt[2 * tid], c1 = cnt[2 * tid + 1];
    ssum[tid] = c0 + c1;
    __syncthreads();
    for (int off = 1; off < 256; off <<= 1) {
        int v = (tid >= off) ? ssum[tid - off] : 0;
        __syncthreads();
        ssum[tid] += v;
        __syncthreads();
    }
    int texcl = (tid == 0) ? 0 : ssum[tid - 1];
    scn[2 * tid] = texcl;
    scn[2 * tid + 1] = texcl + c0;
#pragma unroll
    for (int i = tid; i < NBUCK; i += 256) {
        int c = cnt[i];
        gbase[i] = c ? atomicAdd(&bcur[i], c) : 0;
    }
    __syncthreads();

    for (int i = tid; i < EPB; i += 256) {
        int s = src[ebase + i], d = dst[ebase + i];
        int b = d >> 8;
        int rank = atomicAdd(&cntB[b], 1);
        sEdge[scn[b] + rank] = make_uint2((unsigned)s, (unsigned)d);
    }
    __syncthreads();

    for (int i = tid; i < EPB; i += 256) {
        uint2 ed = sEdge[i];
        int b = (int)(ed.y >> 8);
        scratch[gbase[b] + (i - scn[b])] = ed;
    }
}

__global__ __launch_bounds__(256) void k_fillB(const int* __restrict__ row_ptr,
                                               const uint2* __restrict__ scratch,
                                               int* __restrict__ cursor,
                                               int* __restrict__ csr) {
    int b = blockIdx.x;
    int s = row_ptr[b << 8];
    int endNode = (b + 1) << 8; if (endNode > NN) endNode = NN;
    int e = row_ptr[endNode];
    for (int i = s + threadIdx.x; i < e; i += 256) {
        uint2 ed = scratch[i];
        int p = atomicAdd(&cursor[ed.y], 1);
        csr[p] = (int)ed.x;
    }
}

// ---------------- x -> fp16 (RTN) ----------------
__global__ void k_x2h(const float* __restrict__ x, unsigned short* __restrict__ xh) {
    int idx = blockIdx.x * 256 + threadIdx.x;     // over float4s, NN*128/4 total
    float4 v = ((const float4*)x)[idx];
    ushort4v h;
    h.x = f2h(v.x);
    h.y = f2h(v.y);
    h.z = f2h(v.z);
    h.w = f2h(v.w);
    ((ushort4v*)xh)[idx] = h;
}

// ---------------- weight: W[k][n] fp32 -> Wt [n][k] fp16 ----------------
struct WPack {
    const float* w[5];
    unsigned short* t[5];
};

__global__ void k_w2h(WPack p) {
    int which = blockIdx.x >> 6;
    int idx = (blockIdx.x & 63) * 256 + threadIdx.x; // over n*128+k
    int n = idx >> 7, k = idx & 127;
    p.t[which][idx] = f2h(p.w[which][k * 128 + n]);
}

// ---------------- aggregation (fp16): 16 lanes x 16B per row, 4-way unroll ----------------
__global__ __launch_bounds__(256) void k_agg(const unsigned short* __restrict__ h,
                                             const int* __restrict__ row_ptr,
                                             const int* __restrict__ csr,
                                             unsigned short* __restrict__ u) {
    int g   = threadIdx.x >> 4;         // 0..15
    int l16 = threadIdx.x & 15;
    int node = blockIdx.x * 16 + g;     // 6250 blocks * 16 = 100000 exactly
    int lofs = l16 * 8;                 // 8 fp16 = 16 B per lane
    size_t base = (size_t)node * F + lofs;
    ushort8v sh = *(const ushort8v*)&h[base];
    float a[8];
#pragma unroll
    for (int k = 0; k < 8; ++k) a[k] = h2f(sh[k]);
    int s = row_ptr[node], e = row_ptr[node + 1];
    int p = s;
    for (; p + 4 <= e; p += 4) {
        int j0 = csr[p], j1 = csr[p + 1], j2 = csr[p + 2], j3 = csr[p + 3];
        ushort8v v0 = *(const ushort8v*)&h[(size_t)j0 * F + lofs];
        ushort8v v1 = *(const ushort8v*)&h[(size_t)j1 * F + lofs];
        ushort8v v2 = *(const ushort8v*)&h[(size_t)j2 * F + lofs];
        ushort8v v3 = *(const ushort8v*)&h[(size_t)j3 * F + lofs];
#pragma unroll
        for (int k = 0; k < 8; ++k)
            a[k] += (h2f(v0[k]) + h2f(v1[k])) + (h2f(v2[k]) + h2f(v3[k]));
    }
    if (p + 2 <= e) {
        int j0 = csr[p], j1 = csr[p + 1];
        ushort8v v0 = *(const ushort8v*)&h[(size_t)j0 * F + lofs];
        ushort8v v1 = *(const ushort8v*)&h[(size_t)j1 * F + lofs];
#pragma unroll
        for (int k = 0; k < 8; ++k) a[k] += h2f(v0[k]) + h2f(v1[k]);
        p += 2;
    }
    if (p < e) {
        int j0 = csr[p];
        ushort8v v0 = *(const ushort8v*)&h[(size_t)j0 * F + lofs];
#pragma unroll
        for (int k = 0; k < 8; ++k) a[k] += h2f(v0[k]);
    }
    ushort8v o;
#pragma unroll
    for (int k = 0; k < 8; ++k) o[k] = f2h(a[k]);
    *(ushort8v*)&u[base] = o;
}

// ---------------- MLP layer: 128-row tile, quadrant waves (64 rows x 64 cols), fp16 ----------
// wave w: rg=w>>1 rows [64rg,64rg+64), cg=w&1 cols [64cg,64cg+64).
// L3==0: H = (relu(A@W1+b1))@W2 + b2, fp16.  L3==1: out = relu(A@W1+b1)@w32 + b32, fp32.
template <int L3>
__global__ __launch_bounds__(256, 3) void k_mlp(const unsigned short* __restrict__ A,
                                                const unsigned short* __restrict__ W1,
                                                const float* __restrict__ b1,
                                                const unsigned short* __restrict__ W2,
                                                const float* __restrict__ b2,
                                                const float* __restrict__ w32,
                                                const float* __restrict__ b32,
                                                unsigned short* __restrict__ H,
                                                float* __restrict__ out) {
    __shared__ __align__(16) unsigned short sA[128 * 128];   // 32 KB

    const int tid = threadIdx.x;
    const int row0 = blockIdx.x * 128;
    const int wave = tid >> 6;
    const int lane = tid & 63;
    const int m16  = lane & 15;
    const int quad = lane >> 4;
    const int rg   = wave >> 1;          // 0..1
    const int cg   = wave & 1;           // 0..1

    // ---- stage A tile: lane-contiguous global reads, XOR-swizzled LDS writes ----
    {
        const ushort8v* g = (const ushort8v*)(A + (size_t)row0 * F);
#pragma unroll
        for (int i = 0; i < 8; ++i) {
            int fg = i * 256 + tid;              // 0..2047
            int r = fg >> 4, u = fg & 15;
            ushort8v v = {};
            if (row0 + r < NN) v = g[fg];
            *(ushort8v*)&sA[r * 128 + ((u ^ (r & 15)) << 3)] = v;
        }
    }
    __syncthreads();

    // ---- GEMM1 (quadrant) ----
    f32x4 acc[4][4] = {};
#pragma unroll
    for (int ks = 0; ks < 4; ++ks) {
        f16x8 a[4];
#pragma unroll
        for (int rt = 0; rt < 4; ++rt) {
            int rowL = rg * 64 + rt * 16 + m16;
            int u = ks * 4 + quad;
            a[rt] = *(const f16x8*)&sA[rowL * 128 + ((u ^ (rowL & 15)) << 3)];
        }
#pragma unroll
        for (int ct = 0; ct < 4; ++ct) {
            int widx = (cg * 64 + ct * 16 + m16) * 128 + ks * 32 + quad * 8;
            f16x8 b = *(const f16x8*)&W1[widx];
#pragma unroll
            for (int rt = 0; rt < 4; ++rt)
                acc[rt][ct] = __builtin_amdgcn_mfma_f32_16x16x32_f16(a[rt], b, acc[rt][ct], 0, 0, 0);
        }
    }

    if (L3) {
        // partial dot over this wave's 64 cols; combine across cg via LDS (alias sA)
        float* psf = (float*)sA;     // 128 rows x 2 cg
        __syncthreads();             // all sA reads complete before overwrite
#pragma unroll
        for (int rt = 0; rt < 4; ++rt) {
            float s[4] = {0.f, 0.f, 0.f, 0.f};
#pragma unroll
            for (int ct = 0; ct < 4; ++ct) {
                int col = cg * 64 + ct * 16 + m16;
                float bv = b1[col];
                float wv = w32[col];
#pragma unroll
                for (int i = 0; i < 4; ++i) {
                    float v = fmaxf(acc[rt][ct][i] + bv, 0.f);
                    s[i] += v * wv;
                }
            }
#pragma unroll
            for (int i = 0; i < 4; ++i) {
#pragma unroll
                for (int mask = 1; mask < 16; mask <<= 1)
                    s[i] += __shfl_xor(s[i], mask, 64);
            }
            if (m16 == 0) {
#pragma unroll
                for (int i = 0; i < 4; ++i) {
                    int rowL = rg * 64 + rt * 16 + quad * 4 + i;
                    psf[rowL * 2 + cg] = s[i];
                }
            }
        }
        __syncthreads();
        if (tid < 128) {
            int row = row0 + tid;
            if (row < NN) out[row] = psf[tid * 2] + psf[tid * 2 + 1] + b32[0];
        }
        return;
    }

    // ---- h1 = relu(acc+b1) -> fp16 into LDS quadrant (C-layout -> A-layout) ----
    __syncthreads();
#pragma unroll
    for (int rt = 0; rt < 4; ++rt) {
#pragma unroll
        for (int ct = 0; ct < 4; ++ct) {
            int col = cg * 64 + ct * 16 + m16;
            float bv = b1[col];
#pragma unroll
            for (int i = 0; i < 4; ++i) {
                int rL = rg * 64 + rt * 16 + quad * 4 + i;
                float v = fmaxf(acc[rt][ct][i] + bv, 0.f);
                sA[rL * 128 + (((col >> 3) ^ (rL & 15)) << 3) + (col & 7)] = f2h(v);
            }
        }
    }
    __syncthreads();

    // ---- GEMM2 (quadrant) ----
    f32x4 acc2[4][4] = {};
#pragma unroll
    for (int ks = 0; ks < 4; ++ks) {
        f16x8 a[4];
#pragma unroll
        for (int rt = 0; rt < 4; ++rt) {
            int rowL = rg * 64 + rt * 16 + m16;
            int u = ks * 4 + quad;
            a[rt] = *(const f16x8*)&sA[rowL * 128 + ((u ^ (rowL & 15)) << 3)];
        }
#pragma unroll
        for (int ct = 0; ct < 4; ++ct) {
            int widx = (cg * 64 + ct * 16 + m16) * 128 + ks * 32 + quad * 8;
            f16x8 b = *(const f16x8*)&W2[widx];
#pragma unroll
            for (int rt = 0; rt < 4; ++rt)
                acc2[rt][ct] = __builtin_amdgcn_mfma_f32_16x16x32_f16(a[rt], b, acc2[rt][ct], 0, 0, 0);
        }
    }

    // ---- epilogue: bias -> fp16 -> LDS -> coalesced store ----
    __syncthreads();
#pragma unroll
    for (int rt = 0; rt < 4; ++rt) {
#pragma unroll
        for (int ct = 0; ct < 4; ++ct) {
            int col = cg * 64 + ct * 16 + m16;
            float bv = b2[col];
#pragma unroll
            for (int i = 0; i < 4; ++i) {
                int rL = rg * 64 + rt * 16 + quad * 4 + i;
                float v = acc2[rt][ct][i] + bv;
                sA[rL * 128 + (((col >> 3) ^ (rL & 15)) << 3) + (col & 7)] = f2h(v);
            }
        }
    }
    __syncthreads();
    {
        ushort8v* go = (ushort8v*)(H + (size_t)row0 * F);
#pragma unroll
        for (int i = 0; i < 8; ++i) {
            int fg = i * 256 + tid;
            int r = fg >> 4, u = fg & 15;
            if (row0 + r < NN)
                go[fg] = *(const ushort8v*)&sA[r * 128 + ((u ^ (r & 15)) << 3)];
        }
    }
}

// ---------------- launch ----------------
static inline size_t align256(size_t x) { return (x + 255) & ~(size_t)255; }

extern "C" void kernel_launch(void* const* d_in, const int* in_sizes, int n_in,
                              void* d_out, int out_size, void* d_ws, size_t ws_size,
                              hipStream_t stream) {
    const float* x   = (const float*)d_in[0];
    const int*   ei  = (const int*)d_in[1];
    const float* w11 = (const float*)d_in[2];
    const float* b11 = (const float*)d_in[3];
    const float* w12 = (const float*)d_in[4];
    const float* b12 = (const float*)d_in[5];
    const float* w21 = (const float*)d_in[6];
    const float* b21 = (const float*)d_in[7];
    const float* w22 = (const float*)d_in[8];
    const float* b22 = (const float*)d_in[9];
    const float* w31 = (const float*)d_in[10];
    const float* b31 = (const float*)d_in[11];
    const float* w32 = (const float*)d_in[12];
    const float* b32 = (const float*)d_in[13];
    float* out = (float*)d_out;

    const int* src = ei;
    const int* dst = ei + NE;

    char* ws = (char*)d_ws;
    size_t off = 0;
    unsigned short* Abuf = (unsigned short*)(ws + off); off += align256((size_t)NN * F * 2);
    unsigned short* Bbuf = (unsigned short*)(ws + off); off += align256((size_t)NN * F * 2);
    int* deg     = (int*)(ws + off); off += align256((size_t)NN * 4);
    int* row_ptr = (int*)(ws + off); off += align256((size_t)(NN + 1) * 4);
    int* cursor  = (int*)(ws + off); off += align256((size_t)NN * 4);
    int* partial = (int*)(ws + off); off += align256((size_t)NB_SCAN * 4);
    int* bcur    = (int*)(ws + off); off += align256((size_t)NBUCK * 4);
    int* csr     = (int*)(ws + off); off += align256((size_t)NE * 4);
    uint2* scratch = (uint2*)(ws + off); off += align256((size_t)NE * 8);
    unsigned short* wt[5];
    for (int i = 0; i < 5; ++i) {
        wt[i] = (unsigned short*)(ws + off); off += align256((size_t)128 * 128 * 2);
    }
    (void)ws_size;

    // ---- weight + input conversion ----
    WPack wp;
    wp.w[0] = w11; wp.w[1] = w12; wp.w[2] = w21; wp.w[3] = w22; wp.w[4] = w31;
    for (int i = 0; i < 5; ++i) wp.t[i] = wt[i];
    k_w2h<<<320, 256, 0, stream>>>(wp);
    k_x2h<<<(NN * F / 4 + 255) / 256, 256, 0, stream>>>(x, Abuf);

    // ---- CSR build ----
    (void)hipMemsetAsync(deg, 0, (size_t)NN * 4, stream);
    k_hist<<<2048, 256, 0, stream>>>(dst, deg);
    k_scan_part<<<NB_SCAN, 256, 0, stream>>>(deg, partial);
    k_scan_mid<<<1, 64, 0, stream>>>(partial);
    k_scan_final<<<NB_SCAN, 256, 0, stream>>>(deg, partial, row_ptr, cursor);
    k_bcur<<<(NBUCK + 255) / 256, 256, 0, stream>>>(row_ptr, bcur);
    k_scatterA<<<256, 256, 0, stream>>>(src, dst, bcur, scratch);
    k_fillB<<<NBUCK, 256, 0, stream>>>(row_ptr, scratch, cursor, csr);

    const int aggBlocks = NN / 16;              // 6250
    const int mlpBlocks = (NN + 127) / 128;     // 782

    // ---- layer 1 ----
    k_agg<<<aggBlocks, 256, 0, stream>>>(Abuf, row_ptr, csr, Bbuf);
    k_mlp<0><<<mlpBlocks, 256, 0, stream>>>(Bbuf, wt[0], b11, wt[1], b12,
                                            nullptr, nullptr, Abuf, nullptr);
    // ---- layer 2 ----
    k_agg<<<aggBlocks, 256, 0, stream>>>(Abuf, row_ptr, csr, Bbuf);
    k_mlp<0><<<mlpBlocks, 256, 0, stream>>>(Bbuf, wt[2], b21, wt[3], b22,
                                            nullptr, nullptr, Abuf, nullptr);
    // ---- layer 3 ----
    k_agg<<<aggBlocks, 256, 0, stream>>>(Abuf, row_ptr, csr, Bbuf);
    k_mlp<1><<<mlpBlocks, 256, 0, stream>>>(Bbuf, wt[4], b31, nullptr, nullptr,
                                            w32, b32, nullptr, out);
}

// Round 11
// 442.224 us; speedup vs baseline: 1.5685x; 1.2055x over previous
//
#include <hip/hip_runtime.h>

#define NN 100000
#define NE 1600000
#define F 128
#define NBUCK ((NN + 255) >> 8)                         // 391 buckets of 256 nodes
#define EPB (NE / 256)                                  // 6250 edges per scatter block

typedef _Float16 f16x8 __attribute__((ext_vector_type(8)));
typedef float    f32x4 __attribute__((ext_vector_type(4)));
typedef unsigned short ushort8v __attribute__((ext_vector_type(8)));
typedef unsigned short ushort4v __attribute__((ext_vector_type(4)));

__device__ inline unsigned short f2h(float f) {
    _Float16 h = (_Float16)f;                       // RTN
    return __builtin_bit_cast(unsigned short, h);
}
__device__ inline float h2f(unsigned short u) {
    return (float)__builtin_bit_cast(_Float16, u);
}

// ---------------- CSR build (bucket-level only; no node histogram) ----------------
// bucket counts via LDS privatization: 1 global atomic per (block,bucket)
__global__ __launch_bounds__(256) void k_bhist(const int* __restrict__ dst, int* __restrict__ bcnt) {
    __shared__ int sc[NBUCK];
    for (int i = threadIdx.x; i < NBUCK; i += 256) sc[i] = 0;
    __syncthreads();
    int stride = gridDim.x * 256;
    for (int e = blockIdx.x * 256 + threadIdx.x; e < NE; e += stride)
        atomicAdd(&sc[dst[e] >> 8], 1);
    __syncthreads();
    for (int i = threadIdx.x; i < NBUCK; i += 256) {
        int c = sc[i];
        if (c) atomicAdd(&bcnt[i], c);
    }
}

// exclusive scan over 391 bucket counts -> bbase, bcur
__global__ void k_bscan(const int* __restrict__ bcnt, int* __restrict__ bbase, int* __restrict__ bcur) {
    __shared__ int s[512];
    int t = threadIdx.x;
    int v = (t < NBUCK) ? bcnt[t] : 0;
    s[t] = v;
    __syncthreads();
    for (int off = 1; off < 512; off <<= 1) {
        int u = (t >= off) ? s[t - off] : 0;
        __syncthreads();
        s[t] += u;
        __syncthreads();
    }
    int excl = s[t] - v;
    if (t < NBUCK) { bbase[t] = excl; bcur[t] = excl; }
    if (t == 0) bbase[NBUCK] = NE;
}

// Pass A: LDS counting-sort each 6250-edge chunk by bucket; write bucket-grouped packed
// words (dlocal<<24 | src) into scratch (uint, half the traffic of uint2).
__global__ __launch_bounds__(256) void k_scatterA(const int* __restrict__ src,
                                                  const int* __restrict__ dst,
                                                  int* __restrict__ bcur,
                                                  unsigned* __restrict__ scratch) {
    __shared__ uint2 sEdge[EPB];          // 50 KB
    __shared__ int cnt[512];
    __shared__ int scn[512];
    __shared__ int cntB[512];
    __shared__ int gbase[512];
    __shared__ int ssum[256];

    const int tid = threadIdx.x;
    const int ebase = blockIdx.x * EPB;

#pragma unroll
    for (int i = tid; i < 512; i += 256) { cnt[i] = 0; cntB[i] = 0; }
    __syncthreads();

    for (int i = tid; i < EPB; i += 256) {
        int b = dst[ebase + i] >> 8;
        atomicAdd(&cnt[b], 1);
    }
    __syncthreads();

    int c0 = cnt[2 * tid], c1 = cnt[2 * tid + 1];
    ssum[tid] = c0 + c1;
    __syncthreads();
    for (int off = 1; off < 256; off <<= 1) {
        int v = (tid >= off) ? ssum[tid - off] : 0;
        __syncthreads();
        ssum[tid] += v;
        __syncthreads();
    }
    int texcl = (tid == 0) ? 0 : ssum[tid - 1];
    scn[2 * tid] = texcl;
    scn[2 * tid + 1] = texcl + c0;
#pragma unroll
    for (int i = tid; i < NBUCK; i += 256) {
        int c = cnt[i];
        gbase[i] = c ? atomicAdd(&bcur[i], c) : 0;
    }
    __syncthreads();

    for (int i = tid; i < EPB; i += 256) {
        int s = src[ebase + i], d = dst[ebase + i];
        int b = d >> 8;
        int rank = atomicAdd(&cntB[b], 1);
        sEdge[scn[b] + rank] = make_uint2((unsigned)s, (unsigned)d);
    }
    __syncthreads();

    for (int i = tid; i < EPB; i += 256) {
        uint2 ed = sEdge[i];
        int b = (int)(ed.y >> 8);
        unsigned w = ((ed.y & 255u) << 24) | ed.x;
        scratch[gbase[b] + (i - scn[b])] = w;
    }
}

// Pass B: one block per bucket. LDS histogram of 256 local nodes -> row_ptr + LDS cursors,
// then scatter src into csr (all cursor atomics in LDS; csr writes confined to ~16KB).
__global__ __launch_bounds__(256) void k_fillB(const int* __restrict__ bbase,
                                               const unsigned* __restrict__ scratch,
                                               int* __restrict__ row_ptr,
                                               int* __restrict__ csr) {
    __shared__ int cnt[256];
    __shared__ int s[256];
    __shared__ int cur[256];
    int b = blockIdx.x;
    int base = bbase[b], end = bbase[b + 1];
    int t = threadIdx.x;
    cnt[t] = 0;
    __syncthreads();
    for (int i = base + t; i < end; i += 256)
        atomicAdd(&cnt[scratch[i] >> 24], 1);
    __syncthreads();
    int v = cnt[t];
    s[t] = v;
    __syncthreads();
    for (int off = 1; off < 256; off <<= 1) {
        int u = (t >= off) ? s[t - off] : 0;
        __syncthreads();
        s[t] += u;
        __syncthreads();
    }
    int excl = s[t] - v;
    int node = (b << 8) + t;
    if (node < NN) row_ptr[node] = base + excl;
    if (b == NBUCK - 1 && t == 0) row_ptr[NN] = NE;
    cur[t] = excl;
    __syncthreads();
    for (int i = base + t; i < end; i += 256) {
        unsigned w = scratch[i];
        int n = w >> 24;
        int p = atomicAdd(&cur[n], 1);
        csr[base + p] = (int)(w & 0xFFFFFFu);
    }
}

// ---------------- x -> fp16 (RTN) ----------------
__global__ void k_x2h(const float* __restrict__ x, unsigned short* __restrict__ xh) {
    int idx = blockIdx.x * 256 + threadIdx.x;     // over float4s, NN*128/4 total
    float4 v = ((const float4*)x)[idx];
    ushort4v h;
    h.x = f2h(v.x);
    h.y = f2h(v.y);
    h.z = f2h(v.z);
    h.w = f2h(v.w);
    ((ushort4v*)xh)[idx] = h;
}

// ---------------- weight: W[k][n] fp32 -> Wt [n][k] fp16 ----------------
struct WPack {
    const float* w[5];
    unsigned short* t[5];
};

__global__ void k_w2h(WPack p) {
    int which = blockIdx.x >> 6;
    int idx = (blockIdx.x & 63) * 256 + threadIdx.x; // over n*128+k
    int n = idx >> 7, k = idx & 127;
    p.t[which][idx] = f2h(p.w[which][k * 128 + n]);
}

// ---------------- aggregation (fp16): 16 lanes x 16B per row, 8-way unroll ----------------
__global__ __launch_bounds__(256) void k_agg(const unsigned short* __restrict__ h,
                                             const int* __restrict__ row_ptr,
                                             const int* __restrict__ csr,
                                             unsigned short* __restrict__ u) {
    int g   = threadIdx.x >> 4;         // 0..15
    int l16 = threadIdx.x & 15;
    int node = blockIdx.x * 16 + g;     // 6250 blocks * 16 = 100000 exactly
    int lofs = l16 * 8;                 // 8 fp16 = 16 B per lane
    size_t base = (size_t)node * F + lofs;
    ushort8v sh = *(const ushort8v*)&h[base];
    float a[8];
#pragma unroll
    for (int k = 0; k < 8; ++k) a[k] = h2f(sh[k]);
    int s = row_ptr[node], e = row_ptr[node + 1];
    int p = s;
    for (; p + 8 <= e; p += 8) {
        ushort8v v[8];
#pragma unroll
        for (int q = 0; q < 8; ++q) {
            int j = csr[p + q];
            v[q] = *(const ushort8v*)&h[(size_t)j * F + lofs];
        }
#pragma unroll
        for (int k = 0; k < 8; ++k) {
            float t0 = (h2f(v[0][k]) + h2f(v[1][k])) + (h2f(v[2][k]) + h2f(v[3][k]));
            float t1 = (h2f(v[4][k]) + h2f(v[5][k])) + (h2f(v[6][k]) + h2f(v[7][k]));
            a[k] += t0 + t1;
        }
    }
    if (p + 4 <= e) {
        ushort8v v[4];
#pragma unroll
        for (int q = 0; q < 4; ++q) {
            int j = csr[p + q];
            v[q] = *(const ushort8v*)&h[(size_t)j * F + lofs];
        }
#pragma unroll
        for (int k = 0; k < 8; ++k)
            a[k] += (h2f(v[0][k]) + h2f(v[1][k])) + (h2f(v[2][k]) + h2f(v[3][k]));
        p += 4;
    }
    if (p + 2 <= e) {
        int j0 = csr[p], j1 = csr[p + 1];
        ushort8v v0 = *(const ushort8v*)&h[(size_t)j0 * F + lofs];
        ushort8v v1 = *(const ushort8v*)&h[(size_t)j1 * F + lofs];
#pragma unroll
        for (int k = 0; k < 8; ++k) a[k] += h2f(v0[k]) + h2f(v1[k]);
        p += 2;
    }
    if (p < e) {
        int j0 = csr[p];
        ushort8v v0 = *(const ushort8v*)&h[(size_t)j0 * F + lofs];
#pragma unroll
        for (int k = 0; k < 8; ++k) a[k] += h2f(v0[k]);
    }
    ushort8v o;
#pragma unroll
    for (int k = 0; k < 8; ++k) o[k] = f2h(a[k]);
    *(ushort8v*)&u[base] = o;
}

// ---------------- MLP layer: 64-row tile, 4 col-slice waves (64 rows x 32 cols each) -------
// wave cg: cols [32cg, 32cg+32). W unique per block = 32KB/GEMM, read once; W/row = 0.5KB.
// L3==0: H = (relu(A@W1+b1))@W2 + b2, fp16.  L3==1: out = relu(A@W1+b1)@w32 + b32, fp32.
template <int L3>
__global__ __launch_bounds__(256, 6) void k_mlp(const unsigned short* __restrict__ A,
                                                const unsigned short* __restrict__ W1,
                                                const float* __restrict__ b1,
                                                const unsigned short* __restrict__ W2,
                                                const float* __restrict__ b2,
                                                const float* __restrict__ w32,
                                                const float* __restrict__ b32,
                                                unsigned short* __restrict__ H,
                                                float* __restrict__ out) {
    __shared__ __align__(16) unsigned short sA[64 * 128];   // 16 KB

    const int tid = threadIdx.x;
    const int row0 = blockIdx.x * 64;
    const int cg   = tid >> 6;           // wave id = col slice 0..3
    const int lane = tid & 63;
    const int m16  = lane & 15;
    const int quad = lane >> 4;

    // ---- stage A tile: lane-contiguous global reads, XOR-swizzled LDS writes ----
    {
        const ushort8v* g = (const ushort8v*)(A + (size_t)row0 * F);
#pragma unroll
        for (int i = 0; i < 4; ++i) {
            int fg = i * 256 + tid;              // 0..1023
            int r = fg >> 4, u = fg & 15;
            ushort8v v = {};
            if (row0 + r < NN) v = g[fg];
            *(ushort8v*)&sA[r * 128 + ((u ^ (r & 15)) << 3)] = v;
        }
    }
    __syncthreads();

    // ---- GEMM1 ----
    f32x4 acc[4][2] = {};
#pragma unroll
    for (int ks = 0; ks < 4; ++ks) {
        f16x8 a[4];
#pragma unroll
        for (int rt = 0; rt < 4; ++rt) {
            int rowL = rt * 16 + m16;
            int u = ks * 4 + quad;
            a[rt] = *(const f16x8*)&sA[rowL * 128 + ((u ^ (rowL & 15)) << 3)];
        }
#pragma unroll
        for (int ct = 0; ct < 2; ++ct) {
            int widx = (cg * 32 + ct * 16 + m16) * 128 + ks * 32 + quad * 8;
            f16x8 b = *(const f16x8*)&W1[widx];
#pragma unroll
            for (int rt = 0; rt < 4; ++rt)
                acc[rt][ct] = __builtin_amdgcn_mfma_f32_16x16x32_f16(a[rt], b, acc[rt][ct], 0, 0, 0);
        }
    }

    if (L3) {
        // partial dots over this wave's 32 cols; combine across 4 waves via LDS (alias sA)
        float* psf = (float*)sA;     // 64 rows x 4 cg
        __syncthreads();             // all sA reads complete before overwrite
#pragma unroll
        for (int rt = 0; rt < 4; ++rt) {
            float s[4] = {0.f, 0.f, 0.f, 0.f};
#pragma unroll
            for (int ct = 0; ct < 2; ++ct) {
                int col = cg * 32 + ct * 16 + m16;
                float bv = b1[col];
                float wv = w32[col];
#pragma unroll
                for (int i = 0; i < 4; ++i) {
                    float v = fmaxf(acc[rt][ct][i] + bv, 0.f);
                    s[i] += v * wv;
                }
            }
#pragma unroll
            for (int i = 0; i < 4; ++i) {
#pragma unroll
                for (int mask = 1; mask < 16; mask <<= 1)
                    s[i] += __shfl_xor(s[i], mask, 64);
            }
            if (m16 == 0) {
#pragma unroll
                for (int i = 0; i < 4; ++i) {
                    int rowL = rt * 16 + quad * 4 + i;
                    psf[rowL * 4 + cg] = s[i];
                }
            }
        }
        __syncthreads();
        if (tid < 64) {
            int row = row0 + tid;
            if (row < NN)
                out[row] = (psf[tid * 4] + psf[tid * 4 + 1]) + (psf[tid * 4 + 2] + psf[tid * 4 + 3]) + b32[0];
        }
        return;
    }

    // ---- h1 = relu(acc+b1) -> fp16 into LDS col-slice (C-layout -> A-layout) ----
    __syncthreads();
#pragma unroll
    for (int rt = 0; rt < 4; ++rt) {
#pragma unroll
        for (int ct = 0; ct < 2; ++ct) {
            int col = cg * 32 + ct * 16 + m16;
            float bv = b1[col];
#pragma unroll
            for (int i = 0; i < 4; ++i) {
                int rL = rt * 16 + quad * 4 + i;
                float v = fmaxf(acc[rt][ct][i] + bv, 0.f);
                sA[rL * 128 + (((col >> 3) ^ (rL & 15)) << 3) + (col & 7)] = f2h(v);
            }
        }
    }
    __syncthreads();

    // ---- GEMM2 ----
    f32x4 acc2[4][2] = {};
#pragma unroll
    for (int ks = 0; ks < 4; ++ks) {
        f16x8 a[4];
#pragma unroll
        for (int rt = 0; rt < 4; ++rt) {
            int rowL = rt * 16 + m16;
            int u = ks * 4 + quad;
            a[rt] = *(const f16x8*)&sA[rowL * 128 + ((u ^ (rowL & 15)) << 3)];
        }
#pragma unroll
        for (int ct = 0; ct < 2; ++ct) {
            int widx = (cg * 32 + ct * 16 + m16) * 128 + ks * 32 + quad * 8;
            f16x8 b = *(const f16x8*)&W2[widx];
#pragma unroll
            for (int rt = 0; rt < 4; ++rt)
                acc2[rt][ct] = __builtin_amdgcn_mfma_f32_16x16x32_f16(a[rt], b, acc2[rt][ct], 0, 0, 0);
        }
    }

    // ---- epilogue: bias -> fp16 -> LDS -> coalesced store ----
    __syncthreads();
#pragma unroll
    for (int rt = 0; rt < 4; ++rt) {
#pragma unroll
        for (int ct = 0; ct < 2; ++ct) {
            int col = cg * 32 + ct * 16 + m16;
            float bv = b2[col];
#pragma unroll
            for (int i = 0; i < 4; ++i) {
                int rL = rt * 16 + quad * 4 + i;
                float v = acc2[rt][ct][i] + bv;
                sA[rL * 128 + (((col >> 3) ^ (rL & 15)) << 3) + (col & 7)] = f2h(v);
            }
        }
    }
    __syncthreads();
    {
        ushort8v* go = (ushort8v*)(H + (size_t)row0 * F);
#pragma unroll
        for (int i = 0; i < 4; ++i) {
            int fg = i * 256 + tid;
            int r = fg >> 4, u = fg & 15;
            if (row0 + r < NN)
                go[fg] = *(const ushort8v*)&sA[r * 128 + ((u ^ (r & 15)) << 3)];
        }
    }
}

// ---------------- launch ----------------
static inline size_t align256(size_t x) { return (x + 255) & ~(size_t)255; }

extern "C" void kernel_launch(void* const* d_in, const int* in_sizes, int n_in,
                              void* d_out, int out_size, void* d_ws, size_t ws_size,
                              hipStream_t stream) {
    const float* x   = (const float*)d_in[0];
    const int*   ei  = (const int*)d_in[1];
    const float* w11 = (const float*)d_in[2];
    const float* b11 = (const float*)d_in[3];
    const float* w12 = (const float*)d_in[4];
    const float* b12 = (const float*)d_in[5];
    const float* w21 = (const float*)d_in[6];
    const float* b21 = (const float*)d_in[7];
    const float* w22 = (const float*)d_in[8];
    const float* b22 = (const float*)d_in[9];
    const float* w31 = (const float*)d_in[10];
    const float* b31 = (const float*)d_in[11];
    const float* w32 = (const float*)d_in[12];
    const float* b32 = (const float*)d_in[13];
    float* out = (float*)d_out;

    const int* src = ei;
    const int* dst = ei + NE;

    char* ws = (char*)d_ws;
    size_t off = 0;
    unsigned short* Abuf = (unsigned short*)(ws + off); off += align256((size_t)NN * F * 2);
    unsigned short* Bbuf = (unsigned short*)(ws + off); off += align256((size_t)NN * F * 2);
    int* bcnt    = (int*)(ws + off); off += align256((size_t)NBUCK * 4);
    int* bbase   = (int*)(ws + off); off += align256((size_t)(NBUCK + 1) * 4);
    int* bcur    = (int*)(ws + off); off += align256((size_t)NBUCK * 4);
    int* row_ptr = (int*)(ws + off); off += align256((size_t)(NN + 1) * 4);
    int* csr     = (int*)(ws + off); off += align256((size_t)NE * 4);
    unsigned* scratch = (unsigned*)(ws + off); off += align256((size_t)NE * 4);
    unsigned short* wt[5];
    for (int i = 0; i < 5; ++i) {
        wt[i] = (unsigned short*)(ws + off); off += align256((size_t)128 * 128 * 2);
    }
    (void)ws_size;

    // ---- weight + input conversion ----
    WPack wp;
    wp.w[0] = w11; wp.w[1] = w12; wp.w[2] = w21; wp.w[3] = w22; wp.w[4] = w31;
    for (int i = 0; i < 5; ++i) wp.t[i] = wt[i];
    k_w2h<<<320, 256, 0, stream>>>(wp);
    k_x2h<<<(NN * F / 4 + 255) / 256, 256, 0, stream>>>(x, Abuf);

    // ---- CSR build (bucket-level) ----
    (void)hipMemsetAsync(bcnt, 0, (size_t)NBUCK * 4, stream);
    k_bhist<<<256, 256, 0, stream>>>(dst, bcnt);
    k_bscan<<<1, 512, 0, stream>>>(bcnt, bbase, bcur);
    k_scatterA<<<256, 256, 0, stream>>>(src, dst, bcur, scratch);
    k_fillB<<<NBUCK, 256, 0, stream>>>(bbase, scratch, row_ptr, csr);

    const int aggBlocks = NN / 16;              // 6250
    const int mlpBlocks = (NN + 63) / 64;       // 1563

    // ---- layer 1 ----
    k_agg<<<aggBlocks, 256, 0, stream>>>(Abuf, row_ptr, csr, Bbuf);
    k_mlp<0><<<mlpBlocks, 256, 0, stream>>>(Bbuf, wt[0], b11, wt[1], b12,
                                            nullptr, nullptr, Abuf, nullptr);
    // ---- layer 2 ----
    k_agg<<<aggBlocks, 256, 0, stream>>>(Abuf, row_ptr, csr, Bbuf);
    k_mlp<0><<<mlpBlocks, 256, 0, stream>>>(Bbuf, wt[2], b21, wt[3], b22,
                                            nullptr, nullptr, Abuf, nullptr);
    // ---- layer 3 ----
    k_agg<<<aggBlocks, 256, 0, stream>>>(Abuf, row_ptr, csr, Bbuf);
    k_mlp<1><<<mlpBlocks, 256, 0, stream>>>(Bbuf, wt[4], b31, nullptr, nullptr,
                                            w32, b32, nullptr, out);
}